// Round 7
// baseline (690.984 us; speedup 1.0000x reference)
//
#include <hip/hip_runtime.h>
#include <stdint.h>

// ---- problem constants ----
#define PNUM  8
#define DDIM  512
#define ZDIM  64
#define ADIM  8
#define HDIM  512
#define BATCH 8192
#define KIN   72     // Z + A
#define NKS1  3      // layer1 k-steps of 32 (K padded 72->96)
#define NKS2  16     // layer2 k-steps (K=512)
#define NKS3  16     // layer3 k-steps (K=512)
#define NT12  32     // 512/16 neuron tiles (layers 1,2)
#define NT3   4      // 64/16 z tiles (layer 3)
#define TM    64     // batch rows per block
#define PXP   104    // Xb pitch (bf16 elems): 96 data + 8 pad
#define PHP   520    // H pitch: 512 + 8 pad

typedef __attribute__((ext_vector_type(8))) __bf16 bf16x8;
typedef __attribute__((ext_vector_type(4))) float  f32x4;

// ---- workspace layout ----
// ints (index into (int*)ws):
#define WS_COUNTS_I 0      // 8 counts
#define WS_OFFS_I   16     // 8 offsets
#define WS_CURS_I   32     // 8 cursors
#define WS_FLG_I    42     // 9 flags: 0=lat,1=act,2=W1,3=b1,4=W2,5=b2,6=W3,7=b3 (1=fp32,0=bf16); 8=idx64
#define WS_PERM_I   64     // 8192 row ids
// bytes:
#define WS_W1P_B    40960
#define WS_W2P_B    (WS_W1P_B + 64*NKS1*NT12*1024)            // +6291456
#define WS_W3P_B    (WS_W2P_B + 64*NKS2*NT12*1024)            // +33554432
#define WS_NEED_B   (WS_W3P_B + 64*NKS3*NT3*1024)             // +4194304 -> 44081152

__device__ __forceinline__ float bf2f(ushort h){
  union { unsigned int u; float f; } v; v.u = ((unsigned int)h) << 16; return v.f;
}
__device__ __forceinline__ ushort f2bf(float f){
  union { float f; unsigned int u; } v; v.f = f;
  unsigned int u = v.u;
  return (ushort)((u + 0x7FFFu + ((u >> 16) & 1u)) >> 16);  // RNE
}
__device__ __forceinline__ unsigned int pk2(ushort lo, ushort hi){
  return (unsigned int)lo | ((unsigned int)hi << 16);
}
__device__ __forceinline__ float ldf(const void* p, size_t i, int f32){
  return f32 ? ((const float*)p)[i] : bf2f(((const ushort*)p)[i]);
}
__device__ __forceinline__ int ldidx(const void* p, int t, int i64){
  return i64 ? (int)((const long long*)p)[t] : ((const int*)p)[t];
}
__device__ __forceinline__ float4 ldbias4(const void* b, size_t off, int f32){
  if (f32) return *(const float4*)((const float*)b + off);
  ushort4 q = *(const ushort4*)((const ushort*)b + off);
  float4 r; r.x = bf2f(q.x); r.y = bf2f(q.y); r.z = bf2f(q.z); r.w = bf2f(q.w);
  return r;
}

// ---------- zero ws control words (in-graph; ws is poisoned 0xAA pre-launch) --
__global__ void k_zero(int* __restrict__ wsi){
  wsi[threadIdx.x] = 0;   // ints 0..63: counts/offs/curs/flags
}

// ---------- per-tensor runtime dtype detection ----------
// One wave per tensor. Statistic: bits[14:7] of each 32-bit word. bf16 data ->
// low halfword is a genuine bf16 sample -> exponent in [100,150] ~always.
// fp32 data -> those are uniform mantissa bits -> ~20% in band. Threshold 40/64.
// Wave 8: idx width probe (int64 -> all odd words zero; values are 0..7).
__global__ void k_detect(const unsigned int* __restrict__ lat,
                         const unsigned int* __restrict__ act,
                         const unsigned int* __restrict__ w1,
                         const unsigned int* __restrict__ bb1,
                         const unsigned int* __restrict__ w2,
                         const unsigned int* __restrict__ bb2,
                         const unsigned int* __restrict__ w3,
                         const unsigned int* __restrict__ bb3,
                         const unsigned int* __restrict__ idx,
                         int* __restrict__ wsi){
  int t = threadIdx.x >> 6, lane = threadIdx.x & 63;
  if (t > 8) return;
  if (t == 8){
    unsigned long long nz = __ballot(idx[2 * lane + 1] != 0u);
    if (lane == 0) wsi[WS_FLG_I + 8] = (nz == 0ull) ? 1 : 0;
    return;
  }
  const unsigned int* ptrs[8] = {lat, act, w1, bb1, w2, bb2, w3, bb3};
  unsigned int u = ptrs[t][lane];
  unsigned int e = (u >> 7) & 0xFFu;
  unsigned long long ib = __ballot(e >= 100u && e <= 150u);
  if (lane == 0) wsi[WS_FLG_I + t] = (__popcll(ib) < 40) ? 1 : 0;  // 1 = fp32
}

// ---------- row sorting by outer policy ----------
__global__ void k_count(const void* __restrict__ idx, int* __restrict__ wsi){
  int t = blockIdx.x * 256 + threadIdx.x;
  int i64 = wsi[WS_FLG_I + 8];
  if (t < BATCH) atomicAdd(&wsi[WS_COUNTS_I + ldidx(idx, t, i64)], 1);
}
__global__ void k_scan(int* __restrict__ wsi){
  if (threadIdx.x == 0){
    int off = 0;
    for (int i = 0; i < PNUM; i++){
      wsi[WS_OFFS_I + i] = off;
      wsi[WS_CURS_I + i] = off;
      off += wsi[WS_COUNTS_I + i];
    }
  }
}
__global__ void k_scatter(const void* __restrict__ idx, int* __restrict__ wsi){
  int t = blockIdx.x * 256 + threadIdx.x;
  int i64 = wsi[WS_FLG_I + 8];
  if (t < BATCH){
    int pos = atomicAdd(&wsi[WS_CURS_I + ldidx(idx, t, i64)], 1);
    wsi[WS_PERM_I + pos] = t;
  }
}

// ---------- weight packing into MFMA A-fragment order (bf16 out) ----------
// frag f = (pair*nks + ks)*ntiles + nt; lane -> n = nt*16 + (lane&15),
// k = ks*32 + (lane>>4)*8 + j  (0 if k >= Ksrc)
__global__ void k_pack(const void* __restrict__ src, ushort* __restrict__ dst,
                       int Ksrc, int nks, int ntiles, int N,
                       const int* __restrict__ wsi, int flg){
  int nt = blockIdx.x, ks = blockIdx.y, pair = blockIdx.z;
  int lane = threadIdx.x;
  int f32 = wsi[WS_FLG_I + flg];
  int n  = nt * 16 + (lane & 15);
  int kg = lane >> 4;
  unsigned int vv[4];
  #pragma unroll
  for (int j = 0; j < 4; j++){
    int k0 = ks * 32 + kg * 8 + 2 * j;
    int k1 = k0 + 1;
    ushort lo = (k0 < Ksrc) ? f2bf(ldf(src, ((size_t)pair * Ksrc + k0) * N + n, f32)) : (ushort)0;
    ushort hi = (k1 < Ksrc) ? f2bf(ldf(src, ((size_t)pair * Ksrc + k1) * N + n, f32)) : (ushort)0;
    vv[j] = pk2(lo, hi);
  }
  uint4 val = make_uint4(vv[0], vv[1], vv[2], vv[3]);
  size_t f = (size_t)(pair * nks + ks) * ntiles + nt;
  *(uint4*)(dst + f * 512 + (size_t)lane * 8) = val;
}

// ---------- fused 3-layer MLP ----------
// Transposed compute: D[n][m] = sum_k W[k][n] * X[m][k].
// A slot = packed weights (lane&15 -> n, quad*8+j -> k),
// B slot = activations [m][k] rows in LDS (lane&15 -> m, quad*8+j -> k).
// C layout (m89-verified): col=lane&15 -> m, row=quad*4+reg -> n.
// Output dtype follows latents' measured dtype (ref: zeros_like(latents)).
__global__ void __launch_bounds__(256, 1) k_mlp(
    const void* __restrict__ latents, const void* __restrict__ actions,
    const void* __restrict__ b1, const void* __restrict__ b2,
    const void* __restrict__ b3,
    const int* __restrict__ wsi,
    const ushort* __restrict__ w1p, const ushort* __restrict__ w2p,
    const ushort* __restrict__ w3p,
    void* __restrict__ out, int out_elems)
{
  __shared__ __align__(16) ushort Xb [TM * PXP];   // 13312 B
  __shared__ __align__(16) ushort H1s[TM * PHP];   // 66560 B
  __shared__ __align__(16) ushort H2s[TM * PHP];   // 66560 B
  __shared__ int rowid[TM];

  const int io = blockIdx.z, p = blockIdx.y, tile = blockIdx.x;
  const int cnt = wsi[WS_COUNTS_I + io];
  if (tile * TM >= cnt) return;
  const int r0    = wsi[WS_OFFS_I + io] + tile * TM;
  const int mrows = min(TM, cnt - tile * TM);
  const int pair  = io * PNUM + p;
  const int tid   = threadIdx.x;
  const int fLat  = wsi[WS_FLG_I + 0];
  const int fAct  = wsi[WS_FLG_I + 1];
  const int fB1   = wsi[WS_FLG_I + 3];
  const int fB2   = wsi[WS_FLG_I + 5];
  const int fB3   = wsi[WS_FLG_I + 7];

  // ---- stage X tile: rows 0..63, chunks of 8 elems (64 lat + 8 act + 24 zero)
  for (int task = tid; task < 64 * 16; task += 256){
    int r = task >> 4, c = task & 15;
    if (c >= 13) continue;
    uint4 val = make_uint4(0u, 0u, 0u, 0u);
    if (r < mrows){
      int row = wsi[WS_PERM_I + r0 + r];
      if (c == 8) rowid[r] = row;
      if (c < 9){
        int f32 = (c < 8) ? fLat : fAct;
        if (f32){
          const float* sf = (c < 8)
            ? ((const float*)latents + (size_t)row * DDIM + p * ZDIM + c * 8)
            : ((const float*)actions + (size_t)row * ADIM);
          float4 f0 = *(const float4*)sf;
          float4 f1 = *(const float4*)(sf + 4);
          val = make_uint4(pk2(f2bf(f0.x), f2bf(f0.y)),
                           pk2(f2bf(f0.z), f2bf(f0.w)),
                           pk2(f2bf(f1.x), f2bf(f1.y)),
                           pk2(f2bf(f1.z), f2bf(f1.w)));
        } else {
          const ushort* sh = (c < 8)
            ? ((const ushort*)latents + (size_t)row * DDIM + p * ZDIM + c * 8)
            : ((const ushort*)actions + (size_t)row * ADIM);
          val = *(const uint4*)sh;
        }
      }
    } else if (c == 8) rowid[r] = 0;
    *(uint4*)(Xb + r * PXP + c * 8) = val;
  }
  __syncthreads();

  const int w = tid >> 6, lane = tid & 63;
  const int lm = lane & 15, lq = lane >> 4;
  const uint4* w1v = (const uint4*)w1p;
  const uint4* w2v = (const uint4*)w2p;
  const uint4* w3v = (const uint4*)w3p;
  const f32x4 zero4 = {0.f, 0.f, 0.f, 0.f};

  // ================= layer 1: Xb(64x96) -> H1(64x512), relu =================
  for (int np = 0; np < 2; np++){
    const int ntb = w * 8 + np * 4;
    f32x4 acc[4][4];
    #pragma unroll
    for (int a = 0; a < 4; a++)
      #pragma unroll
      for (int m = 0; m < 4; m++) acc[a][m] = zero4;

    for (int ks = 0; ks < NKS1; ks++){
      uint4 af[4], bf[4];
      #pragma unroll
      for (int a = 0; a < 4; a++)
        af[a] = w1v[((size_t)(pair * NKS1 + ks) * NT12 + ntb + a) * 64 + lane];
      #pragma unroll
      for (int m = 0; m < 4; m++)
        bf[m] = *(const uint4*)(Xb + (size_t)(m * 16 + lm) * PXP + ks * 32 + lq * 8);
      #pragma unroll
      for (int a = 0; a < 4; a++)
        #pragma unroll
        for (int m = 0; m < 4; m++)
          acc[a][m] = __builtin_amdgcn_mfma_f32_16x16x32_bf16(
              __builtin_bit_cast(bf16x8, af[a]), __builtin_bit_cast(bf16x8, bf[m]),
              acc[a][m], 0, 0, 0);
    }
    #pragma unroll
    for (int a = 0; a < 4; a++){
      int n0 = (ntb + a) * 16 + lq * 4;
      float4 bq = ldbias4(b1, (size_t)pair * HDIM + n0, fB1);
      #pragma unroll
      for (int m = 0; m < 4; m++){
        ushort4 o;
        o.x = f2bf(fmaxf(acc[a][m][0] + bq.x, 0.f));
        o.y = f2bf(fmaxf(acc[a][m][1] + bq.y, 0.f));
        o.z = f2bf(fmaxf(acc[a][m][2] + bq.z, 0.f));
        o.w = f2bf(fmaxf(acc[a][m][3] + bq.w, 0.f));
        *(ushort4*)(H1s + (size_t)(m * 16 + lm) * PHP + n0) = o;
      }
    }
  }
  __syncthreads();

  // ================= layer 2: H1 -> H2, relu (depth-1 prefetch) =================
  for (int np = 0; np < 2; np++){
    const int ntb = w * 8 + np * 4;
    f32x4 acc[4][4];
    #pragma unroll
    for (int a = 0; a < 4; a++)
      #pragma unroll
      for (int m = 0; m < 4; m++) acc[a][m] = zero4;

    uint4 af[4], bf[4];
    #pragma unroll
    for (int a = 0; a < 4; a++)
      af[a] = w2v[((size_t)(pair * NKS2 + 0) * NT12 + ntb + a) * 64 + lane];
    #pragma unroll
    for (int m = 0; m < 4; m++)
      bf[m] = *(const uint4*)(H1s + (size_t)(m * 16 + lm) * PHP + lq * 8);

    for (int ks = 0; ks < NKS2; ks++){
      uint4 afn[4], bfn[4];
      const bool more = (ks + 1 < NKS2);
      if (more){
        #pragma unroll
        for (int a = 0; a < 4; a++)
          afn[a] = w2v[((size_t)(pair * NKS2 + ks + 1) * NT12 + ntb + a) * 64 + lane];
        #pragma unroll
        for (int m = 0; m < 4; m++)
          bfn[m] = *(const uint4*)(H1s + (size_t)(m * 16 + lm) * PHP + (ks + 1) * 32 + lq * 8);
      }
      #pragma unroll
      for (int a = 0; a < 4; a++)
        #pragma unroll
        for (int m = 0; m < 4; m++)
          acc[a][m] = __builtin_amdgcn_mfma_f32_16x16x32_bf16(
              __builtin_bit_cast(bf16x8, af[a]), __builtin_bit_cast(bf16x8, bf[m]),
              acc[a][m], 0, 0, 0);
      if (more){
        #pragma unroll
        for (int a = 0; a < 4; a++){ af[a] = afn[a]; bf[a] = bfn[a]; }
      }
    }
    #pragma unroll
    for (int a = 0; a < 4; a++){
      int n0 = (ntb + a) * 16 + lq * 4;
      float4 bq = ldbias4(b2, (size_t)pair * HDIM + n0, fB2);
      #pragma unroll
      for (int m = 0; m < 4; m++){
        ushort4 o;
        o.x = f2bf(fmaxf(acc[a][m][0] + bq.x, 0.f));
        o.y = f2bf(fmaxf(acc[a][m][1] + bq.y, 0.f));
        o.z = f2bf(fmaxf(acc[a][m][2] + bq.z, 0.f));
        o.w = f2bf(fmaxf(acc[a][m][3] + bq.w, 0.f));
        *(ushort4*)(H2s + (size_t)(m * 16 + lm) * PHP + n0) = o;
      }
    }
  }
  __syncthreads();

  // ================= layer 3: H2 -> out (wave w owns z-tile w) =================
  {
    f32x4 acc[4];
    #pragma unroll
    for (int m = 0; m < 4; m++) acc[m] = zero4;
    for (int ks = 0; ks < NKS3; ks++){
      uint4 af = w3v[((size_t)(pair * NKS3 + ks) * NT3 + w) * 64 + lane];
      #pragma unroll
      for (int m = 0; m < 4; m++){
        uint4 bf = *(const uint4*)(H2s + (size_t)(m * 16 + lm) * PHP + ks * 32 + lq * 8);
        acc[m] = __builtin_amdgcn_mfma_f32_16x16x32_bf16(
            __builtin_bit_cast(bf16x8, af), __builtin_bit_cast(bf16x8, bf),
            acc[m], 0, 0, 0);
      }
    }
    int z0 = w * 16 + lq * 4;
    float4 bq = ldbias4(b3, (size_t)pair * ZDIM + z0, fB3);
    #pragma unroll
    for (int m = 0; m < 4; m++){
      int mm = m * 16 + lm;
      if (mm < mrows){
        int row = rowid[mm];
        size_t oidx = (size_t)row * DDIM + p * ZDIM + z0;
        if (oidx + 4 > (size_t)out_elems) continue;
        if (fLat){   // latents fp32 -> output fp32 (ref: zeros_like(latents))
          float4 o;
          o.x = acc[m][0] + bq.x;
          o.y = acc[m][1] + bq.y;
          o.z = acc[m][2] + bq.z;
          o.w = acc[m][3] + bq.w;
          *(float4*)((float*)out + oidx) = o;
        } else {
          ushort4 o;
          o.x = f2bf(acc[m][0] + bq.x);
          o.y = f2bf(acc[m][1] + bq.y);
          o.z = f2bf(acc[m][2] + bq.z);
          o.w = f2bf(acc[m][3] + bq.w);
          *(ushort4*)((ushort*)out + oidx) = o;
        }
      }
    }
  }
}

extern "C" void kernel_launch(void* const* d_in, const int* in_sizes, int n_in,
                              void* d_out, int out_size, void* d_ws, size_t ws_size,
                              hipStream_t stream){
  if (n_in < 9) return;
  const void* latents = d_in[0];
  const void* actions = d_in[1];
  const void* pidx    = d_in[2];
  const void* W1      = d_in[3];
  const void* b1      = d_in[4];
  const void* W2      = d_in[5];
  const void* b2      = d_in[6];
  const void* W3      = d_in[7];
  const void* b3      = d_in[8];

  if (ws_size < (size_t)WS_NEED_B) return;

  int*    wsi = (int*)d_ws;
  char*   wsb = (char*)d_ws;
  ushort* w1p = (ushort*)(wsb + WS_W1P_B);
  ushort* w2p = (ushort*)(wsb + WS_W2P_B);
  ushort* w3p = (ushort*)(wsb + WS_W3P_B);

  k_zero   <<<1, 64, 0, stream>>>(wsi);
  k_detect <<<1, 576, 0, stream>>>(
      (const unsigned int*)latents, (const unsigned int*)actions,
      (const unsigned int*)W1, (const unsigned int*)b1,
      (const unsigned int*)W2, (const unsigned int*)b2,
      (const unsigned int*)W3, (const unsigned int*)b3,
      (const unsigned int*)pidx, wsi);
  k_count  <<<BATCH/256, 256, 0, stream>>>(pidx, wsi);
  k_scan   <<<1, 64, 0, stream>>>(wsi);
  k_scatter<<<BATCH/256, 256, 0, stream>>>(pidx, wsi);
  k_pack<<<dim3(NT12, NKS1, 64), 64, 0, stream>>>(W1, w1p, KIN,  NKS1, NT12, HDIM, wsi, 2);
  k_pack<<<dim3(NT12, NKS2, 64), 64, 0, stream>>>(W2, w2p, HDIM, NKS2, NT12, HDIM, wsi, 4);
  k_pack<<<dim3(NT3,  NKS3, 64), 64, 0, stream>>>(W3, w3p, HDIM, NKS3, NT3,  ZDIM, wsi, 6);
  k_mlp<<<dim3(BATCH/TM, PNUM, PNUM), 256, 0, stream>>>(
      latents, actions, b1, b2, b3, wsi, w1p, w2p, w3p, d_out, out_size);
}

// Round 8
// 376.793 us; speedup vs baseline: 1.8339x; 1.8339x over previous
//
#include <hip/hip_runtime.h>
#include <stdint.h>

// ---- problem constants ----
#define PNUM  8
#define DDIM  512
#define ZDIM  64
#define ADIM  8
#define HDIM  512
#define BATCH 8192
#define KIN   72     // Z + A
#define NKS1  3      // layer1 k-steps of 32 (K padded 72->96)
#define NKS2  16     // layer2 k-steps (K=512)
#define NKS3  16     // layer3 k-steps (K=512)
#define NT12  32     // 512/16 neuron tiles (layers 1,2)
#define NT3   4      // 64/16 z tiles (layer 3)
#define TM    32     // batch rows per block (32: LDS 73KB -> 2 blocks/CU)
#define PXP   104    // Xb pitch (bf16 elems): 96 data + 8 pad
#define PHP   520    // H pitch: 512 + 8 pad

typedef __attribute__((ext_vector_type(8))) __bf16 bf16x8;
typedef __attribute__((ext_vector_type(4))) float  f32x4;

// ---- workspace layout ----
#define WS_COUNTS_I 0      // 8 counts
#define WS_OFFS_I   16     // 8 offsets
#define WS_CURS_I   32     // 8 cursors
#define WS_FLG_I    42     // 9 flags: 0=lat,1=act,2=W1,3=b1,4=W2,5=b2,6=W3,7=b3 (1=fp32,0=bf16); 8=idx64
#define WS_PERM_I   64     // 8192 row ids
#define WS_W1P_B    40960
#define WS_W2P_B    (WS_W1P_B + 64*NKS1*NT12*1024)            // +6291456
#define WS_W3P_B    (WS_W2P_B + 64*NKS2*NT12*1024)            // +33554432
#define WS_NEED_B   (WS_W3P_B + 64*NKS3*NT3*1024)             // -> 44081152

__device__ __forceinline__ float bf2f(ushort h){
  union { unsigned int u; float f; } v; v.u = ((unsigned int)h) << 16; return v.f;
}
__device__ __forceinline__ ushort f2bf(float f){
  union { float f; unsigned int u; } v; v.f = f;
  unsigned int u = v.u;
  return (ushort)((u + 0x7FFFu + ((u >> 16) & 1u)) >> 16);  // RNE
}
__device__ __forceinline__ unsigned int pk2(ushort lo, ushort hi){
  return (unsigned int)lo | ((unsigned int)hi << 16);
}
__device__ __forceinline__ float ldf(const void* p, size_t i, int f32){
  return f32 ? ((const float*)p)[i] : bf2f(((const ushort*)p)[i]);
}
__device__ __forceinline__ int ldidx(const void* p, int t, int i64){
  return i64 ? (int)((const long long*)p)[t] : ((const int*)p)[t];
}
__device__ __forceinline__ float4 ldbias4(const void* b, size_t off, int f32){
  if (f32) return *(const float4*)((const float*)b + off);
  ushort4 q = *(const ushort4*)((const ushort*)b + off);
  float4 r; r.x = bf2f(q.x); r.y = bf2f(q.y); r.z = bf2f(q.z); r.w = bf2f(q.w);
  return r;
}

// ---------- zero ws control words (in-graph) ----------
__global__ void k_zero(int* __restrict__ wsi){
  wsi[threadIdx.x] = 0;
}

// ---------- per-tensor runtime dtype detection ----------
__global__ void k_detect(const unsigned int* __restrict__ lat,
                         const unsigned int* __restrict__ act,
                         const unsigned int* __restrict__ w1,
                         const unsigned int* __restrict__ bb1,
                         const unsigned int* __restrict__ w2,
                         const unsigned int* __restrict__ bb2,
                         const unsigned int* __restrict__ w3,
                         const unsigned int* __restrict__ bb3,
                         const unsigned int* __restrict__ idx,
                         int* __restrict__ wsi){
  int t = threadIdx.x >> 6, lane = threadIdx.x & 63;
  if (t > 8) return;
  if (t == 8){
    unsigned long long nz = __ballot(idx[2 * lane + 1] != 0u);
    if (lane == 0) wsi[WS_FLG_I + 8] = (nz == 0ull) ? 1 : 0;
    return;
  }
  const unsigned int* ptrs[8] = {lat, act, w1, bb1, w2, bb2, w3, bb3};
  unsigned int u = ptrs[t][lane];
  unsigned int e = (u >> 7) & 0xFFu;
  unsigned long long ib = __ballot(e >= 100u && e <= 150u);
  if (lane == 0) wsi[WS_FLG_I + t] = (__popcll(ib) < 40) ? 1 : 0;  // 1 = fp32
}

// ---------- row sorting by outer policy ----------
__global__ void k_count(const void* __restrict__ idx, int* __restrict__ wsi){
  int t = blockIdx.x * 256 + threadIdx.x;
  int i64 = wsi[WS_FLG_I + 8];
  if (t < BATCH) atomicAdd(&wsi[WS_COUNTS_I + ldidx(idx, t, i64)], 1);
}
__global__ void k_scan(int* __restrict__ wsi){
  if (threadIdx.x == 0){
    int off = 0;
    for (int i = 0; i < PNUM; i++){
      wsi[WS_OFFS_I + i] = off;
      wsi[WS_CURS_I + i] = off;
      off += wsi[WS_COUNTS_I + i];
    }
  }
}
__global__ void k_scatter(const void* __restrict__ idx, int* __restrict__ wsi){
  int t = blockIdx.x * 256 + threadIdx.x;
  int i64 = wsi[WS_FLG_I + 8];
  if (t < BATCH){
    int pos = atomicAdd(&wsi[WS_CURS_I + ldidx(idx, t, i64)], 1);
    wsi[WS_PERM_I + pos] = t;
  }
}

// ---------- weight packing, coalesced via LDS transpose ----------
// Block 256 thr handles 4 n-tiles x 1 ks (64 n x 32 k) for one pair.
// Read: wave w reads k-rows w*8..w*8+7, lane = n (contiguous 256B fp32 rows).
// Write: group tid>>6 = local tile; frag lane -> n = lane&15, k = (lane>>4)*8+j.
__global__ void k_pack(const void* __restrict__ src, ushort* __restrict__ dst,
                       int Ksrc, int nks, int ntiles, int N,
                       const int* __restrict__ wsi, int flg){
  __shared__ ushort T[32][66];
  const int ks = blockIdx.y, pair = blockIdx.z, nt0 = blockIdx.x * 4;
  const int f32 = wsi[WS_FLG_I + flg];
  const int w = threadIdx.x >> 6, lane = threadIdx.x & 63;
  #pragma unroll
  for (int kk = 0; kk < 8; kk++){
    int krow = w * 8 + kk;
    int k = ks * 32 + krow;
    int n = nt0 * 16 + lane;
    ushort v = 0;
    if (k < Ksrc) v = f2bf(ldf(src, ((size_t)pair * Ksrc + k) * N + n, f32));
    T[krow][lane] = v;
  }
  __syncthreads();
  const int lm = lane & 15, lq = lane >> 4;
  unsigned int vv[4];
  #pragma unroll
  for (int j = 0; j < 4; j++){
    ushort lo = T[lq * 8 + 2 * j    ][w * 16 + lm];
    ushort hi = T[lq * 8 + 2 * j + 1][w * 16 + lm];
    vv[j] = pk2(lo, hi);
  }
  uint4 val = make_uint4(vv[0], vv[1], vv[2], vv[3]);
  size_t f = (size_t)(pair * nks + ks) * ntiles + (nt0 + w);
  *(uint4*)(dst + f * 512 + (size_t)lane * 8) = val;
}

// ---------- fused 3-layer MLP ----------
// Transposed compute: D[n][m] = sum_k W[k][n] * X[m][k].
// A = packed weights, B = activations [m][k] in LDS.
// C layout (m89-verified): m = lane&15, n = (lane>>4)*4 + reg.
// Grid: x = pair (64) -> same-pair blocks share XCD (id%8 heuristic), y = tile.
__global__ void __launch_bounds__(256, 2) k_mlp(
    const void* __restrict__ latents, const void* __restrict__ actions,
    const void* __restrict__ b1, const void* __restrict__ b2,
    const void* __restrict__ b3,
    const int* __restrict__ wsi,
    const ushort* __restrict__ w1p, const ushort* __restrict__ w2p,
    const ushort* __restrict__ w3p,
    void* __restrict__ out, int out_elems)
{
  __shared__ __align__(16) ushort Xb [TM * PXP];   // 6656 B
  __shared__ __align__(16) ushort H1s[TM * PHP];   // 33280 B
  __shared__ __align__(16) ushort H2s[TM * PHP];   // 33280 B
  __shared__ int rowid[TM];

  const int io = blockIdx.x >> 3, p = blockIdx.x & 7, tile = blockIdx.y;
  const int cnt = wsi[WS_COUNTS_I + io];
  if (tile * TM >= cnt) return;
  const int r0    = wsi[WS_OFFS_I + io] + tile * TM;
  const int mrows = min(TM, cnt - tile * TM);
  const int pair  = io * PNUM + p;
  const int tid   = threadIdx.x;
  const int fLat  = wsi[WS_FLG_I + 0];
  const int fAct  = wsi[WS_FLG_I + 1];
  const int fB1   = wsi[WS_FLG_I + 3];
  const int fB2   = wsi[WS_FLG_I + 5];
  const int fB3   = wsi[WS_FLG_I + 7];

  // ---- stage X tile: TM rows, chunks of 8 elems (64 lat + 8 act + 24 zero)
  for (int task = tid; task < TM * 16; task += 256){
    int r = task >> 4, c = task & 15;
    if (c >= 13) continue;
    uint4 val = make_uint4(0u, 0u, 0u, 0u);
    if (r < mrows){
      int row = wsi[WS_PERM_I + r0 + r];
      if (c == 8) rowid[r] = row;
      if (c < 9){
        int f32 = (c < 8) ? fLat : fAct;
        if (f32){
          const float* sf = (c < 8)
            ? ((const float*)latents + (size_t)row * DDIM + p * ZDIM + c * 8)
            : ((const float*)actions + (size_t)row * ADIM);
          float4 f0 = *(const float4*)sf;
          float4 f1 = *(const float4*)(sf + 4);
          val = make_uint4(pk2(f2bf(f0.x), f2bf(f0.y)),
                           pk2(f2bf(f0.z), f2bf(f0.w)),
                           pk2(f2bf(f1.x), f2bf(f1.y)),
                           pk2(f2bf(f1.z), f2bf(f1.w)));
        } else {
          const ushort* sh = (c < 8)
            ? ((const ushort*)latents + (size_t)row * DDIM + p * ZDIM + c * 8)
            : ((const ushort*)actions + (size_t)row * ADIM);
          val = *(const uint4*)sh;
        }
      }
    } else if (c == 8) rowid[r] = 0;
    *(uint4*)(Xb + r * PXP + c * 8) = val;
  }
  __syncthreads();

  const int w = tid >> 6, lane = tid & 63;
  const int lm = lane & 15, lq = lane >> 4;
  const uint4* w1v = (const uint4*)w1p;
  const uint4* w2v = (const uint4*)w2p;
  const uint4* w3v = (const uint4*)w3p;
  const f32x4 zero4 = {0.f, 0.f, 0.f, 0.f};

  // ================= layer 1: Xb(TMx96) -> H1(TMx512), relu =================
  for (int np = 0; np < 2; np++){
    const int ntb = np * 16 + w * 4;
    f32x4 acc[4][2];
    #pragma unroll
    for (int a = 0; a < 4; a++)
      #pragma unroll
      for (int m = 0; m < 2; m++) acc[a][m] = zero4;

    for (int ks = 0; ks < NKS1; ks++){
      uint4 af[4], bf[2];
      #pragma unroll
      for (int a = 0; a < 4; a++)
        af[a] = w1v[((size_t)(pair * NKS1 + ks) * NT12 + ntb + a) * 64 + lane];
      #pragma unroll
      for (int m = 0; m < 2; m++)
        bf[m] = *(const uint4*)(Xb + (size_t)(m * 16 + lm) * PXP + ks * 32 + lq * 8);
      #pragma unroll
      for (int a = 0; a < 4; a++)
        #pragma unroll
        for (int m = 0; m < 2; m++)
          acc[a][m] = __builtin_amdgcn_mfma_f32_16x16x32_bf16(
              __builtin_bit_cast(bf16x8, af[a]), __builtin_bit_cast(bf16x8, bf[m]),
              acc[a][m], 0, 0, 0);
    }
    #pragma unroll
    for (int a = 0; a < 4; a++){
      int n0 = (ntb + a) * 16 + lq * 4;
      float4 bq = ldbias4(b1, (size_t)pair * HDIM + n0, fB1);
      #pragma unroll
      for (int m = 0; m < 2; m++){
        ushort4 o;
        o.x = f2bf(fmaxf(acc[a][m][0] + bq.x, 0.f));
        o.y = f2bf(fmaxf(acc[a][m][1] + bq.y, 0.f));
        o.z = f2bf(fmaxf(acc[a][m][2] + bq.z, 0.f));
        o.w = f2bf(fmaxf(acc[a][m][3] + bq.w, 0.f));
        *(ushort4*)(H1s + (size_t)(m * 16 + lm) * PHP + n0) = o;
      }
    }
  }
  __syncthreads();

  // ================= layer 2: H1 -> H2, relu (depth-1 prefetch) =================
  for (int np = 0; np < 2; np++){
    const int ntb = np * 16 + w * 4;
    f32x4 acc[4][2];
    #pragma unroll
    for (int a = 0; a < 4; a++)
      #pragma unroll
      for (int m = 0; m < 2; m++) acc[a][m] = zero4;

    uint4 af[4], bf[2];
    #pragma unroll
    for (int a = 0; a < 4; a++)
      af[a] = w2v[((size_t)(pair * NKS2 + 0) * NT12 + ntb + a) * 64 + lane];
    #pragma unroll
    for (int m = 0; m < 2; m++)
      bf[m] = *(const uint4*)(H1s + (size_t)(m * 16 + lm) * PHP + lq * 8);

    for (int ks = 0; ks < NKS2; ks++){
      uint4 afn[4], bfn[2];
      const bool more = (ks + 1 < NKS2);
      if (more){
        #pragma unroll
        for (int a = 0; a < 4; a++)
          afn[a] = w2v[((size_t)(pair * NKS2 + ks + 1) * NT12 + ntb + a) * 64 + lane];
        #pragma unroll
        for (int m = 0; m < 2; m++)
          bfn[m] = *(const uint4*)(H1s + (size_t)(m * 16 + lm) * PHP + (ks + 1) * 32 + lq * 8);
      }
      #pragma unroll
      for (int a = 0; a < 4; a++)
        #pragma unroll
        for (int m = 0; m < 2; m++)
          acc[a][m] = __builtin_amdgcn_mfma_f32_16x16x32_bf16(
              __builtin_bit_cast(bf16x8, af[a]), __builtin_bit_cast(bf16x8, bf[m]),
              acc[a][m], 0, 0, 0);
      if (more){
        #pragma unroll
        for (int a = 0; a < 4; a++) af[a] = afn[a];
        #pragma unroll
        for (int m = 0; m < 2; m++) bf[m] = bfn[m];
      }
    }
    #pragma unroll
    for (int a = 0; a < 4; a++){
      int n0 = (ntb + a) * 16 + lq * 4;
      float4 bq = ldbias4(b2, (size_t)pair * HDIM + n0, fB2);
      #pragma unroll
      for (int m = 0; m < 2; m++){
        ushort4 o;
        o.x = f2bf(fmaxf(acc[a][m][0] + bq.x, 0.f));
        o.y = f2bf(fmaxf(acc[a][m][1] + bq.y, 0.f));
        o.z = f2bf(fmaxf(acc[a][m][2] + bq.z, 0.f));
        o.w = f2bf(fmaxf(acc[a][m][3] + bq.w, 0.f));
        *(ushort4*)(H2s + (size_t)(m * 16 + lm) * PHP + n0) = o;
      }
    }
  }
  __syncthreads();

  // ================= layer 3: H2 -> out (wave w owns z-tile w) =================
  {
    f32x4 acc[2];
    #pragma unroll
    for (int m = 0; m < 2; m++) acc[m] = zero4;
    for (int ks = 0; ks < NKS3; ks++){
      uint4 af = w3v[((size_t)(pair * NKS3 + ks) * NT3 + w) * 64 + lane];
      #pragma unroll
      for (int m = 0; m < 2; m++){
        uint4 bf = *(const uint4*)(H2s + (size_t)(m * 16 + lm) * PHP + ks * 32 + lq * 8);
        acc[m] = __builtin_amdgcn_mfma_f32_16x16x32_bf16(
            __builtin_bit_cast(bf16x8, af), __builtin_bit_cast(bf16x8, bf),
            acc[m], 0, 0, 0);
      }
    }
    int z0 = w * 16 + lq * 4;
    float4 bq = ldbias4(b3, (size_t)pair * ZDIM + z0, fB3);
    #pragma unroll
    for (int m = 0; m < 2; m++){
      int mm = m * 16 + lm;
      if (mm < mrows){
        int row = rowid[mm];
        size_t oidx = (size_t)row * DDIM + p * ZDIM + z0;
        if (oidx + 4 > (size_t)out_elems) continue;
        if (fLat){   // latents fp32 -> output fp32 (ref: zeros_like(latents))
          float4 o;
          o.x = acc[m][0] + bq.x;
          o.y = acc[m][1] + bq.y;
          o.z = acc[m][2] + bq.z;
          o.w = acc[m][3] + bq.w;
          *(float4*)((float*)out + oidx) = o;
        } else {
          ushort4 o;
          o.x = f2bf(acc[m][0] + bq.x);
          o.y = f2bf(acc[m][1] + bq.y);
          o.z = f2bf(acc[m][2] + bq.z);
          o.w = f2bf(acc[m][3] + bq.w);
          *(ushort4*)((ushort*)out + oidx) = o;
        }
      }
    }
  }
}

extern "C" void kernel_launch(void* const* d_in, const int* in_sizes, int n_in,
                              void* d_out, int out_size, void* d_ws, size_t ws_size,
                              hipStream_t stream){
  if (n_in < 9) return;
  const void* latents = d_in[0];
  const void* actions = d_in[1];
  const void* pidx    = d_in[2];
  const void* W1      = d_in[3];
  const void* b1      = d_in[4];
  const void* W2      = d_in[5];
  const void* b2      = d_in[6];
  const void* W3      = d_in[7];
  const void* b3      = d_in[8];

  if (ws_size < (size_t)WS_NEED_B) return;

  int*    wsi = (int*)d_ws;
  char*   wsb = (char*)d_ws;
  ushort* w1p = (ushort*)(wsb + WS_W1P_B);
  ushort* w2p = (ushort*)(wsb + WS_W2P_B);
  ushort* w3p = (ushort*)(wsb + WS_W3P_B);

  k_zero   <<<1, 64, 0, stream>>>(wsi);
  k_detect <<<1, 576, 0, stream>>>(
      (const unsigned int*)latents, (const unsigned int*)actions,
      (const unsigned int*)W1, (const unsigned int*)b1,
      (const unsigned int*)W2, (const unsigned int*)b2,
      (const unsigned int*)W3, (const unsigned int*)b3,
      (const unsigned int*)pidx, wsi);
  k_count  <<<BATCH/256, 256, 0, stream>>>(pidx, wsi);
  k_scan   <<<1, 64, 0, stream>>>(wsi);
  k_scatter<<<BATCH/256, 256, 0, stream>>>(pidx, wsi);
  k_pack<<<dim3(8, NKS1, 64), 256, 0, stream>>>(W1, w1p, KIN,  NKS1, NT12, HDIM, wsi, 2);
  k_pack<<<dim3(8, NKS2, 64), 256, 0, stream>>>(W2, w2p, HDIM, NKS2, NT12, HDIM, wsi, 4);
  k_pack<<<dim3(1, NKS3, 64), 256, 0, stream>>>(W3, w3p, HDIM, NKS3, NT3,  ZDIM, wsi, 6);
  k_mlp<<<dim3(64, BATCH/TM), 256, 0, stream>>>(
      latents, actions, b1, b2, b3, wsi, w1p, w2p, w3p, d_out, out_size);
}